// Round 1
// baseline (561.832 us; speedup 1.0000x reference)
//
#include <hip/hip_runtime.h>
#include <math.h>

#define CIN  3
#define COUT 24
#define KS   3
#define DIN  16
#define HIN  128
#define HOUT 126
#define DOUT 14
#define WPAD 84   // 81 weights padded to 84 per co (84*4 = 336 B = 21*16, keeps ds_read_b128 aligned)

__global__ __launch_bounds__(128) void conv3d_min_softmax(
    const float* __restrict__ x,
    const float* __restrict__ wgt,
    const float* __restrict__ bias,
    float* __restrict__ out)
{
    __shared__ float wl[COUT * WPAD];
    __shared__ float bl[COUT];

    const int tid = threadIdx.x;
    // stage weights into LDS, padded to 84 per output channel
    for (int i = tid; i < COUT * WPAD; i += 128) {
        int co = i / WPAD;
        int t  = i - co * WPAD;
        wl[i] = (t < 81) ? wgt[co * 81 + t] : 0.0f;
    }
    if (tid < COUT) bl[tid] = bias[tid];
    __syncthreads();

    const int h  = blockIdx.x;   // 0..125
    const int b  = blockIdx.y;   // 0..15
    const int wc = tid;          // 0..127, columns 126/127 idle
    if (wc >= HOUT) return;

    const float* xb = x + (size_t)b * (CIN * DIN * HIN * HIN);

    float m[COUT];
    #pragma unroll
    for (int c = 0; c < COUT; ++c) m[c] = 3.4e38f;

    for (int dp = 0; dp < DOUT; ++dp) {
        // load the 3x3x3x3 input patch for this output pixel & depth slice
        float px[81];
        #pragma unroll
        for (int ci = 0; ci < CIN; ++ci) {
            #pragma unroll
            for (int kd = 0; kd < KS; ++kd) {
                const float* xrow0 =
                    xb + ((size_t)(ci * DIN + dp + kd) * HIN + h) * HIN + wc;
                #pragma unroll
                for (int kh = 0; kh < KS; ++kh) {
                    #pragma unroll
                    for (int kw = 0; kw < KS; ++kw) {
                        px[((ci * KS + kd) * KS + kh) * KS + kw] =
                            xrow0[kh * HIN + kw];
                    }
                }
            }
        }
        // all 24 channels against this patch; weights broadcast from LDS
        for (int co = 0; co < COUT; ++co) {
            const float* wp = &wl[co * WPAD];
            float s0 = 0.0f, s1 = 0.0f, s2 = 0.0f;  // 3-way split to shorten dep chain
            #pragma unroll
            for (int t = 0; t < 27; ++t) {
                s0 = fmaf(px[3 * t + 0], wp[3 * t + 0], s0);
                s1 = fmaf(px[3 * t + 1], wp[3 * t + 1], s1);
                s2 = fmaf(px[3 * t + 2], wp[3 * t + 2], s2);
            }
            float s = (s0 + s1) + s2;
            m[co] = fminf(m[co], s);
        }
    }

    // bias (depth-invariant, commutes with min) + softmax over channels
    float mx = -3.4e38f;
    #pragma unroll
    for (int c = 0; c < COUT; ++c) {
        m[c] += bl[c];
        mx = fmaxf(mx, m[c]);
    }
    float sum = 0.0f;
    #pragma unroll
    for (int c = 0; c < COUT; ++c) {
        m[c] = __expf(m[c] - mx);
        sum += m[c];
    }
    const float r = 1.0f / sum;

    float* ob = out + ((size_t)b * COUT * HOUT + h) * HOUT + wc;
    #pragma unroll
    for (int c = 0; c < COUT; ++c) {
        ob[(size_t)c * HOUT * HOUT] = m[c] * r;
    }
}

extern "C" void kernel_launch(void* const* d_in, const int* in_sizes, int n_in,
                              void* d_out, int out_size, void* d_ws, size_t ws_size,
                              hipStream_t stream) {
    const float* x    = (const float*)d_in[0];
    const float* wgt  = (const float*)d_in[1];
    const float* bias = (const float*)d_in[2];
    float* out        = (float*)d_out;

    dim3 grid(HOUT, 16);   // (h, b)
    dim3 block(128);
    conv3d_min_softmax<<<grid, block, 0, stream>>>(x, wgt, bias, out);
}